// Round 15
// baseline (163.675 us; speedup 1.0000x reference)
//
#include <hip/hip_runtime.h>
#include <math.h>

#define N_NODES 100000
#define N_EDGES 600000
#define NC 41
#define CAP 32                        // bucket capacity (max deg ~23 for Poisson(6) x 100k)
#define BLDB 2048                     // k_build blocks
#define NT32 (N_NODES / 32)           // 3125 32-node tiles

typedef __attribute__((ext_vector_type(8))) short bf16x8;
typedef __attribute__((ext_vector_type(8))) unsigned short u16x8;
typedef __attribute__((ext_vector_type(4))) float f32x4;

static __device__ __forceinline__ unsigned short f2b(float f) {
    unsigned u = __float_as_uint(f);
    unsigned r = ((u >> 16) & 1u) + 0x7fffu;
    return (unsigned short)((u + r) >> 16);
}
static __device__ __forceinline__ float b2f(unsigned short s) {
    return __uint_as_float(((unsigned)s) << 16);
}
static __device__ __forceinline__ u16x8 zero8() {
    u16x8 z;
#pragma unroll
    for (int i = 0; i < 8; ++i) z[i] = 0;
    return z;
}

// ---------- k_build: xb = bf16(x)  INTERLEAVED with  bucket-CSR scatter ----------
// Convert is BW-bound, scatter is request-bound: issue both streams concurrently.
__global__ __launch_bounds__(256) void k_build(const float* __restrict__ x,
                                               unsigned short* __restrict__ xb,
                                               const int* __restrict__ src,
                                               const int* __restrict__ dst,
                                               int* __restrict__ cnt,
                                               int* __restrict__ eidx) {
    int tid = blockIdx.x * 256 + threadIdx.x;
    const int nthr = BLDB * 256;
    const int convN = N_NODES * 16;           // u16x8 items
    int i = tid, e = tid;
    while (i < convN || e < N_EDGES) {
        // one scatter edge (request stream)
        if (e < N_EDGES) {
            int s = src[e];
            int d = dst[e];
            int pos = atomicAdd(&cnt[d], 1);
            if (pos < CAP) eidx[(size_t)d * CAP + pos] = s;
            e += nthr;
        }
        // one convert item (bandwidth stream)
        if (i < convN) {
            float4 lo = ((const float4*)x)[i * 2];
            float4 hi = ((const float4*)x)[i * 2 + 1];
            u16x8 o;
            o[0] = f2b(lo.x); o[1] = f2b(lo.y); o[2] = f2b(lo.z); o[3] = f2b(lo.w);
            o[4] = f2b(hi.x); o[5] = f2b(hi.y); o[6] = f2b(hi.z); o[7] = f2b(hi.w);
            ((u16x8*)xb)[i] = o;
            i += nthr;
        }
    }
}

// ---------- k_aggmm: fused layer-1 gather-aggregate + dual MFMA ----------
// 512 thr = 8 waves; 32-node tile; aggregated rows staged in LDS (no R buffer).
// R_tile = di_d*(di_d*xb[d] + sum di_s*xb[s]) -> rows -> MFMA W1 -> relu+b1
// -> rows -> MFMA W2 -> *di -> h2 (stride 48).
__global__ __launch_bounds__(512) void k_aggmm(const unsigned short* __restrict__ xb,
                                               const int* __restrict__ cnt,
                                               const int* __restrict__ eidx,
                                               const float* __restrict__ W1,
                                               const float* __restrict__ b1,
                                               const float* __restrict__ W2,
                                               unsigned short* __restrict__ h2) {
    __shared__ unsigned short Wt1[128 * 132];
    __shared__ unsigned short Wt2[48 * 132];
    __shared__ unsigned short rows[32 * 136];
    int tid = threadIdx.x;
    for (int i = tid; i < 128 * 128; i += 512) {
        int k = i >> 7, n = i & 127;
        Wt1[n * 132 + k] = f2b(W1[i]);
    }
    for (int i = tid; i < 128 * 48; i += 512) {
        int k = i / 48, n = i % 48;
        Wt2[n * 132 + k] = f2b((n < NC) ? W2[k * NC + n] : 0.f);
    }
    __syncthreads();

    int l = tid & 63, w = tid >> 6;   // 8 waves
    int lr = l & 15, g = l >> 4;
    int rh = w >> 2;                   // stage-1 row half (0/1)
    int cg = w & 3;                    // stage-1 col group
    int rh2 = w / 3, ct = w % 3;       // stage-2 roles, w<6
    int grp = tid >> 4, j = tid & 15;  // gather: node-group 0..31, col-slice 0..15

    bf16x8 f1[2][4];
#pragma unroll
    for (int c = 0; c < 2; ++c) {
        int n = (cg * 2 + c) * 16 + lr;
#pragma unroll
        for (int kt = 0; kt < 4; ++kt) {
            const unsigned short* p = &Wt1[n * 132 + kt * 32 + g * 4];
            short4 lo = *(const short4*)p;
            short4 hi = *(const short4*)(p + 16);
            bf16x8 f;
            f[0] = lo.x; f[1] = lo.y; f[2] = lo.z; f[3] = lo.w;
            f[4] = hi.x; f[5] = hi.y; f[6] = hi.z; f[7] = hi.w;
            f1[c][kt] = f;
        }
    }
    bf16x8 f2[4];
    if (w < 6) {
#pragma unroll
        for (int kt = 0; kt < 4; ++kt) {
            const unsigned short* p = &Wt2[(ct * 16 + lr) * 132 + kt * 32 + g * 4];
            short4 lo = *(const short4*)p;
            short4 hi = *(const short4*)(p + 16);
            bf16x8 f;
            f[0] = lo.x; f[1] = lo.y; f[2] = lo.z; f[3] = lo.w;
            f[4] = hi.x; f[5] = hi.y; f[6] = hi.z; f[7] = hi.w;
            f2[kt] = f;
        }
    }
    float bia0 = b1[(cg * 2) * 16 + lr];
    float bia1 = b1[(cg * 2 + 1) * 16 + lr];

    for (int t = blockIdx.x; t < NT32; t += gridDim.x) {
        // ---- gather-aggregate 32 nodes into rows ----
        {
            int node = t * 32 + grp;
            int deg = min(cnt[node], CAP);
            float di = rsqrtf((float)(deg + 1));
            float acc[8];
            u16x8 v = *(const u16x8*)(xb + (size_t)node * 128 + j * 8);
#pragma unroll
            for (int i = 0; i < 8; ++i) acc[i] = b2f(v[i]) * di;
            const int* ebase = eidx + (size_t)node * CAP;
            int e = 0;
            int s0 = (0 < deg) ? ebase[0] : -1;
            int s1 = (1 < deg) ? ebase[1] : -1;
            u16x8 r0 = zero8(), r1 = zero8();
            int c0 = 0, c1 = 0;
            if (s0 >= 0) { r0 = *(const u16x8*)(xb + (size_t)s0 * 128 + j * 8); c0 = cnt[s0]; }
            if (s1 >= 0) { r1 = *(const u16x8*)(xb + (size_t)s1 * 128 + j * 8); c1 = cnt[s1]; }
            while (s0 >= 0) {
                int s2 = (e + 2 < deg) ? ebase[e + 2] : -1;
                u16x8 r2 = zero8();
                int c2 = 0;
                if (s2 >= 0) { r2 = *(const u16x8*)(xb + (size_t)s2 * 128 + j * 8); c2 = cnt[s2]; }
                float wgt = rsqrtf((float)(c0 + 1));
#pragma unroll
                for (int i = 0; i < 8; ++i) acc[i] = fmaf(b2f(r0[i]), wgt, acc[i]);
                s0 = s1; s1 = s2; c0 = c1; c1 = c2; r0 = r1; r1 = r2; ++e;
            }
            u16x8 o;
#pragma unroll
            for (int i = 0; i < 8; ++i) o[i] = f2b(acc[i] * di);
            *(u16x8*)&rows[grp * 136 + j * 8] = o;
        }
        __syncthreads();

        // ---- stage 1: [16 rows(rh)] x [32 cols(cg)] per wave ----
        f32x4 a0 = {0.f, 0.f, 0.f, 0.f};
        f32x4 a1 = {0.f, 0.f, 0.f, 0.f};
#pragma unroll
        for (int kt = 0; kt < 4; ++kt) {
            const unsigned short* pa = &rows[(rh * 16 + lr) * 136 + kt * 32 + g * 4];
            short4 alo = *(const short4*)pa;
            short4 ahi = *(const short4*)(pa + 16);
            bf16x8 a;
            a[0] = alo.x; a[1] = alo.y; a[2] = alo.z; a[3] = alo.w;
            a[4] = ahi.x; a[5] = ahi.y; a[6] = ahi.z; a[7] = ahi.w;
            a0 = __builtin_amdgcn_mfma_f32_16x16x32_bf16(a, f1[0][kt], a0, 0, 0, 0);
            a1 = __builtin_amdgcn_mfma_f32_16x16x32_bf16(a, f1[1][kt], a1, 0, 0, 0);
        }
        __syncthreads();  // all stage-1 reads of rows done

        // relu(+b1) -> rows (C layout: col = coltile*16+lr, row = rh*16 + g*4 + i)
#pragma unroll
        for (int i = 0; i < 4; ++i) {
            int row = rh * 16 + g * 4 + i;
            rows[row * 136 + (cg * 2) * 16 + lr]     = f2b(fmaxf(a0[i] + bia0, 0.f));
            rows[row * 136 + (cg * 2 + 1) * 16 + lr] = f2b(fmaxf(a1[i] + bia1, 0.f));
        }
        __syncthreads();

        // ---- stage 2: waves 0..5: [16 rows(rh2)] x [16 cols(ct)] ----
        if (w < 6) {
            f32x4 c0 = {0.f, 0.f, 0.f, 0.f};
#pragma unroll
            for (int kt = 0; kt < 4; ++kt) {
                const unsigned short* pa = &rows[(rh2 * 16 + lr) * 136 + kt * 32 + g * 4];
                short4 alo = *(const short4*)pa;
                short4 ahi = *(const short4*)(pa + 16);
                bf16x8 a;
                a[0] = alo.x; a[1] = alo.y; a[2] = alo.z; a[3] = alo.w;
                a[4] = ahi.x; a[5] = ahi.y; a[6] = ahi.z; a[7] = ahi.w;
                c0 = __builtin_amdgcn_mfma_f32_16x16x32_bf16(a, f2[kt], c0, 0, 0, 0);
            }
#pragma unroll
            for (int i = 0; i < 4; ++i) {
                int row = t * 32 + rh2 * 16 + g * 4 + i;
                float dv = rsqrtf((float)(min(cnt[row], CAP) + 1));
                h2[(size_t)row * 48 + ct * 16 + lr] = f2b(c0[i] * dv);
            }
        }
        __syncthreads();
    }
}

// ---------- gather2: out = log_softmax(di * (self + sum h2'[s]) + b2) ----------
// 2 nodes per wave; h2 rows 96 B packed; LDS-staged coalesced float4 output.
__global__ __launch_bounds__(256, 8) void k_gather2(const unsigned short* __restrict__ h2,
                                                    float* __restrict__ out,
                                                    const int* __restrict__ cnt,
                                                    const int* __restrict__ eidx,
                                                    const float* __restrict__ b2) {
    __shared__ float so[8 * NC + 8];  // 8 nodes x 41 outputs (+pad)
    int tid = threadIdx.x;
    int nloc = tid >> 5;
    int node = blockIdx.x * 8 + nloc;
    int l = tid & 31;
    int g = l >> 3, j = l & 7;
    bool act = (j < 6);
    int deg = min(cnt[node], CAP);
    float di = rsqrtf((float)(deg + 1));
    float acc[8];
#pragma unroll
    for (int i = 0; i < 8; ++i) acc[i] = 0.f;
    if (g == 0 && act) {
        u16x8 v = *(const u16x8*)(h2 + (size_t)node * 48 + j * 8);
#pragma unroll
        for (int i = 0; i < 8; ++i) acc[i] = b2f(v[i]);
    }
    const int* ebase = eidx + (size_t)node * CAP;
    int e = g;
    int s0 = (e < deg) ? ebase[e] : -1;
    int s1 = (e + 4 < deg) ? ebase[e + 4] : -1;
    u16x8 r0 = zero8(), r1 = zero8();
    if (s0 >= 0 && act) r0 = *(const u16x8*)(h2 + (size_t)s0 * 48 + j * 8);
    if (s1 >= 0 && act) r1 = *(const u16x8*)(h2 + (size_t)s1 * 48 + j * 8);
    while (s0 >= 0) {
        int s2 = (e + 8 < deg) ? ebase[e + 8] : -1;
        u16x8 r2 = zero8();
        if (s2 >= 0 && act) r2 = *(const u16x8*)(h2 + (size_t)s2 * 48 + j * 8);
#pragma unroll
        for (int i = 0; i < 8; ++i) acc[i] += b2f(r0[i]);
        s0 = s1; s1 = s2; r0 = r1; r1 = r2; e += 4;
    }
#pragma unroll
    for (int i = 0; i < 8; ++i) acc[i] += __shfl_xor(acc[i], 8);
#pragma unroll
    for (int i = 0; i < 8; ++i) acc[i] += __shfl_xor(acc[i], 16);
    int c0 = j * 8;
    float vv[8];
#pragma unroll
    for (int i = 0; i < 8; ++i)
        vv[i] = (act && c0 + i < NC) ? acc[i] * di + b2[c0 + i] : -INFINITY;
    float m = vv[0];
#pragma unroll
    for (int i = 1; i < 8; ++i) m = fmaxf(m, vv[i]);
#pragma unroll
    for (int o = 4; o; o >>= 1) m = fmaxf(m, __shfl_xor(m, o));
    float sm = 0.f;
#pragma unroll
    for (int i = 0; i < 8; ++i) sm += (act && c0 + i < NC) ? expf(vv[i] - m) : 0.f;
#pragma unroll
    for (int o = 4; o; o >>= 1) sm += __shfl_xor(sm, o);
    float lg = logf(sm);
    if (g == 0 && act) {
#pragma unroll
        for (int i = 0; i < 8; ++i) {
            int c = c0 + i;
            if (c < NC) so[nloc * NC + c] = vv[i] - m - lg;
        }
    }
    __syncthreads();
    // coalesced block write: 8 nodes x 41 floats = 328 floats = 82 float4
    float4* ob = (float4*)(out + (size_t)blockIdx.x * (8 * NC));
    const float4* sb = (const float4*)so;
    if (tid < 2 * NC) ob[tid] = sb[tid];
}

extern "C" void kernel_launch(void* const* d_in, const int* in_sizes, int n_in,
                              void* d_out, int out_size, void* d_ws, size_t ws_size,
                              hipStream_t stream) {
    const float* x  = (const float*)d_in[0];
    const float* W1 = (const float*)d_in[1];
    const float* b1 = (const float*)d_in[2];
    const float* W2 = (const float*)d_in[3];
    const float* b2 = (const float*)d_in[4];
    const int*   ei = (const int*)d_in[5];
    const int* src = ei;
    const int* dst = ei + N_EDGES;
    float* out = (float*)d_out;

    char* ws = (char*)d_ws;
    int* cnt  = (int*)ws;                                      // N ints (count = degree)
    int* eidx = (int*)(ws + (1u << 20));                       // N*CAP ints (12.8 MB)
    unsigned short* xb = (unsigned short*)(ws + (15u << 20));  // N*128 bf16 (unscaled)
    unsigned short* h2 = (unsigned short*)(ws + (41u << 20));  // N*48 bf16 (pre-scaled)

    // bucket-CSR build + x->bf16 (interleaved streams; cnt becomes degree)
    hipMemsetAsync(cnt, 0, N_NODES * sizeof(int), stream);
    k_build<<<BLDB, 256, 0, stream>>>(x, xb, src, dst, cnt, eidx);

    // fused layer-1 aggregation + dual-GEMM (R buffer eliminated)
    k_aggmm<<<1024, 512, 0, stream>>>(xb, cnt, eidx, W1, b1, W2, h2);

    // layer-2 aggregation + log_softmax (coalesced output)
    k_gather2<<<N_NODES / 8, 256, 0, stream>>>(h2, out, cnt, eidx, b2);
}

// Round 16
// 151.490 us; speedup vs baseline: 1.0804x; 1.0804x over previous
//
#include <hip/hip_runtime.h>
#include <math.h>

#define N_NODES 100000
#define N_EDGES 600000
#define NC 41
#define CAP 32                        // bucket capacity (max deg ~23 for Poisson(6) x 100k)
#define BLDB 2048                     // k_build blocks

typedef __attribute__((ext_vector_type(8))) short bf16x8;
typedef __attribute__((ext_vector_type(8))) unsigned short u16x8;
typedef __attribute__((ext_vector_type(4))) float f32x4;

static __device__ __forceinline__ unsigned short f2b(float f) {
    unsigned u = __float_as_uint(f);
    unsigned r = ((u >> 16) & 1u) + 0x7fffu;
    return (unsigned short)((u + r) >> 16);
}
static __device__ __forceinline__ float b2f(unsigned short s) {
    return __uint_as_float(((unsigned)s) << 16);
}
static __device__ __forceinline__ u16x8 zero8() {
    u16x8 z;
#pragma unroll
    for (int i = 0; i < 8; ++i) z[i] = 0;
    return z;
}

// ---------- k_build: xb = bf16(x)  INTERLEAVED with  bucket-CSR scatter ----------
// Convert is BW-bound, scatter is request-bound: issue both streams concurrently.
__global__ __launch_bounds__(256) void k_build(const float* __restrict__ x,
                                               unsigned short* __restrict__ xb,
                                               const int* __restrict__ src,
                                               const int* __restrict__ dst,
                                               int* __restrict__ cnt,
                                               int* __restrict__ eidx) {
    int tid = blockIdx.x * 256 + threadIdx.x;
    const int nthr = BLDB * 256;
    const int convN = N_NODES * 16;           // u16x8 items
    int i = tid, e = tid;
    while (i < convN || e < N_EDGES) {
        // one scatter edge (request stream)
        if (e < N_EDGES) {
            int s = src[e];
            int d = dst[e];
            int pos = atomicAdd(&cnt[d], 1);
            if (pos < CAP) eidx[(size_t)d * CAP + pos] = s;
            e += nthr;
        }
        // one convert item (bandwidth stream)
        if (i < convN) {
            float4 lo = ((const float4*)x)[i * 2];
            float4 hi = ((const float4*)x)[i * 2 + 1];
            u16x8 o;
            o[0] = f2b(lo.x); o[1] = f2b(lo.y); o[2] = f2b(lo.z); o[3] = f2b(lo.w);
            o[4] = f2b(hi.x); o[5] = f2b(hi.y); o[6] = f2b(hi.z); o[7] = f2b(hi.w);
            ((u16x8*)xb)[i] = o;
            i += nthr;
        }
    }
}

// ---------- k_aggx: R[d] = bf16( di_d * (di_d*xb[d] + sum di_s*xb[s]) ) ----------
// 16-lane group per node, 2-deep row prefetch, dinv computed inline from cnt.
__global__ __launch_bounds__(256, 8) void k_aggx(const unsigned short* __restrict__ xb,
                                                 const int* __restrict__ cnt,
                                                 const int* __restrict__ eidx,
                                                 unsigned short* __restrict__ R) {
    int tid = threadIdx.x;
    int node = blockIdx.x * 16 + (tid >> 4);
    int j = tid & 15;
    int deg = min(cnt[node], CAP);
    float di = rsqrtf((float)(deg + 1));
    float acc[8];
    {
        u16x8 v = *(const u16x8*)(xb + (size_t)node * 128 + j * 8);
#pragma unroll
        for (int i = 0; i < 8; ++i) acc[i] = b2f(v[i]) * di;  // self: di^2 after final *di
    }
    const int* ebase = eidx + (size_t)node * CAP;
    int e = 0;
    int s0 = (0 < deg) ? ebase[0] : -1;
    int s1 = (1 < deg) ? ebase[1] : -1;
    u16x8 r0 = zero8(), r1 = zero8();
    int c0 = 0, c1 = 0;
    if (s0 >= 0) { r0 = *(const u16x8*)(xb + (size_t)s0 * 128 + j * 8); c0 = cnt[s0]; }
    if (s1 >= 0) { r1 = *(const u16x8*)(xb + (size_t)s1 * 128 + j * 8); c1 = cnt[s1]; }
    while (s0 >= 0) {
        int s2 = (e + 2 < deg) ? ebase[e + 2] : -1;
        u16x8 r2 = zero8();
        int c2 = 0;
        if (s2 >= 0) { r2 = *(const u16x8*)(xb + (size_t)s2 * 128 + j * 8); c2 = cnt[s2]; }
        float w = rsqrtf((float)(c0 + 1));
#pragma unroll
        for (int i = 0; i < 8; ++i) acc[i] = fmaf(b2f(r0[i]), w, acc[i]);
        s0 = s1; s1 = s2; c0 = c1; c1 = c2; r0 = r1; r1 = r2; ++e;
    }
    u16x8 o;
#pragma unroll
    for (int i = 0; i < 8; ++i) o[i] = f2b(acc[i] * di);
    *(u16x8*)(R + (size_t)node * 128 + j * 8) = o;
}

// ---------- k_mm: h2' = dinv * (relu(R@W1 + b1) @ W2)  (streaming dual-MFMA) ----------
// h2 rows packed at stride 48 (96 B).
__global__ __launch_bounds__(512) void k_mm(const unsigned short* __restrict__ R,
                                            const float* __restrict__ W1,
                                            const float* __restrict__ b1,
                                            const float* __restrict__ W2,
                                            const int* __restrict__ cnt,
                                            unsigned short* __restrict__ h2) {
    __shared__ unsigned short Wt1[128 * 132];
    __shared__ unsigned short Wt2[48 * 132];
    __shared__ unsigned short rows[32 * 136];
    int tid = threadIdx.x;
    for (int i = tid; i < 128 * 128; i += 512) {
        int k = i >> 7, n = i & 127;
        Wt1[n * 132 + k] = f2b(W1[i]);
    }
    for (int i = tid; i < 128 * 48; i += 512) {
        int k = i / 48, n = i % 48;
        Wt2[n * 132 + k] = f2b((n < NC) ? W2[k * NC + n] : 0.f);
    }
    __syncthreads();

    int l = tid & 63, w = tid >> 6;   // 8 waves
    int lr = l & 15, g = l >> 4;
    int rh = w >> 2;                   // stage-1 row half (0/1)
    int cg = w & 3;                    // stage-1 col group (2 col-tiles each)
    int rh2 = w / 3, ct = w % 3;       // stage-2 roles, w<6

    bf16x8 f1[2][4];
#pragma unroll
    for (int c = 0; c < 2; ++c) {
        int n = (cg * 2 + c) * 16 + lr;
#pragma unroll
        for (int kt = 0; kt < 4; ++kt) {
            const unsigned short* p = &Wt1[n * 132 + kt * 32 + g * 4];
            short4 lo = *(const short4*)p;
            short4 hi = *(const short4*)(p + 16);
            bf16x8 f;
            f[0] = lo.x; f[1] = lo.y; f[2] = lo.z; f[3] = lo.w;
            f[4] = hi.x; f[5] = hi.y; f[6] = hi.z; f[7] = hi.w;
            f1[c][kt] = f;
        }
    }
    bf16x8 f2[4];
    if (w < 6) {
#pragma unroll
        for (int kt = 0; kt < 4; ++kt) {
            const unsigned short* p = &Wt2[(ct * 16 + lr) * 132 + kt * 32 + g * 4];
            short4 lo = *(const short4*)p;
            short4 hi = *(const short4*)(p + 16);
            bf16x8 f;
            f[0] = lo.x; f[1] = lo.y; f[2] = lo.z; f[3] = lo.w;
            f[4] = hi.x; f[5] = hi.y; f[6] = hi.z; f[7] = hi.w;
            f2[kt] = f;
        }
    }
    float bia0 = b1[(cg * 2) * 16 + lr];
    float bia1 = b1[(cg * 2 + 1) * 16 + lr];

    int srow = tid >> 4, scol = tid & 15;  // staging: row 0..31, 8-col slice
    for (int t = blockIdx.x; t < N_NODES / 32; t += gridDim.x) {
        // coalesced stage: 32 rows x 256B
        *(u16x8*)&rows[srow * 136 + scol * 8] =
            *(const u16x8*)(R + ((size_t)t * 32 + srow) * 128 + scol * 8);
        __syncthreads();

        // stage 1: [16 rows(rh)] x [32 cols(cg)] per wave
        f32x4 a0 = {0.f, 0.f, 0.f, 0.f};
        f32x4 a1 = {0.f, 0.f, 0.f, 0.f};
#pragma unroll
        for (int kt = 0; kt < 4; ++kt) {
            const unsigned short* pa = &rows[(rh * 16 + lr) * 136 + kt * 32 + g * 4];
            short4 alo = *(const short4*)pa;
            short4 ahi = *(const short4*)(pa + 16);
            bf16x8 a;
            a[0] = alo.x; a[1] = alo.y; a[2] = alo.z; a[3] = alo.w;
            a[4] = ahi.x; a[5] = ahi.y; a[6] = ahi.z; a[7] = ahi.w;
            a0 = __builtin_amdgcn_mfma_f32_16x16x32_bf16(a, f1[0][kt], a0, 0, 0, 0);
            a1 = __builtin_amdgcn_mfma_f32_16x16x32_bf16(a, f1[1][kt], a1, 0, 0, 0);
        }
        __syncthreads();  // all stage-1 reads of rows done

        // relu(+b1) -> rows (C layout: col = coltile*16+lr, row = rh*16 + g*4 + i)
#pragma unroll
        for (int i = 0; i < 4; ++i) {
            int row = rh * 16 + g * 4 + i;
            rows[row * 136 + (cg * 2) * 16 + lr]     = f2b(fmaxf(a0[i] + bia0, 0.f));
            rows[row * 136 + (cg * 2 + 1) * 16 + lr] = f2b(fmaxf(a1[i] + bia1, 0.f));
        }
        __syncthreads();

        // stage 2: waves 0..5: [16 rows(rh2)] x [16 cols(ct)]
        if (w < 6) {
            f32x4 c0 = {0.f, 0.f, 0.f, 0.f};
#pragma unroll
            for (int kt = 0; kt < 4; ++kt) {
                const unsigned short* pa = &rows[(rh2 * 16 + lr) * 136 + kt * 32 + g * 4];
                short4 alo = *(const short4*)pa;
                short4 ahi = *(const short4*)(pa + 16);
                bf16x8 a;
                a[0] = alo.x; a[1] = alo.y; a[2] = alo.z; a[3] = alo.w;
                a[4] = ahi.x; a[5] = ahi.y; a[6] = ahi.z; a[7] = ahi.w;
                c0 = __builtin_amdgcn_mfma_f32_16x16x32_bf16(a, f2[kt], c0, 0, 0, 0);
            }
#pragma unroll
            for (int i = 0; i < 4; ++i) {
                int row = t * 32 + rh2 * 16 + g * 4 + i;
                float dv = rsqrtf((float)(min(cnt[row], CAP) + 1));
                h2[(size_t)row * 48 + ct * 16 + lr] = f2b(c0[i] * dv);
            }
        }
        __syncthreads();
    }
}

// ---------- gather2: out = log_softmax(di * (self + sum h2'[s]) + b2) ----------
// 2 nodes per wave; h2 rows 96 B packed; LDS-staged coalesced float4 output.
__global__ __launch_bounds__(256, 8) void k_gather2(const unsigned short* __restrict__ h2,
                                                    float* __restrict__ out,
                                                    const int* __restrict__ cnt,
                                                    const int* __restrict__ eidx,
                                                    const float* __restrict__ b2) {
    __shared__ float so[8 * NC + 8];  // 8 nodes x 41 outputs (+pad)
    int tid = threadIdx.x;
    int nloc = tid >> 5;
    int node = blockIdx.x * 8 + nloc;
    int l = tid & 31;
    int g = l >> 3, j = l & 7;
    bool act = (j < 6);
    int deg = min(cnt[node], CAP);
    float di = rsqrtf((float)(deg + 1));
    float acc[8];
#pragma unroll
    for (int i = 0; i < 8; ++i) acc[i] = 0.f;
    if (g == 0 && act) {
        u16x8 v = *(const u16x8*)(h2 + (size_t)node * 48 + j * 8);
#pragma unroll
        for (int i = 0; i < 8; ++i) acc[i] = b2f(v[i]);
    }
    const int* ebase = eidx + (size_t)node * CAP;
    int e = g;
    int s0 = (e < deg) ? ebase[e] : -1;
    int s1 = (e + 4 < deg) ? ebase[e + 4] : -1;
    u16x8 r0 = zero8(), r1 = zero8();
    if (s0 >= 0 && act) r0 = *(const u16x8*)(h2 + (size_t)s0 * 48 + j * 8);
    if (s1 >= 0 && act) r1 = *(const u16x8*)(h2 + (size_t)s1 * 48 + j * 8);
    while (s0 >= 0) {
        int s2 = (e + 8 < deg) ? ebase[e + 8] : -1;
        u16x8 r2 = zero8();
        if (s2 >= 0 && act) r2 = *(const u16x8*)(h2 + (size_t)s2 * 48 + j * 8);
#pragma unroll
        for (int i = 0; i < 8; ++i) acc[i] += b2f(r0[i]);
        s0 = s1; s1 = s2; r0 = r1; r1 = r2; e += 4;
    }
#pragma unroll
    for (int i = 0; i < 8; ++i) acc[i] += __shfl_xor(acc[i], 8);
#pragma unroll
    for (int i = 0; i < 8; ++i) acc[i] += __shfl_xor(acc[i], 16);
    int c0 = j * 8;
    float vv[8];
#pragma unroll
    for (int i = 0; i < 8; ++i)
        vv[i] = (act && c0 + i < NC) ? acc[i] * di + b2[c0 + i] : -INFINITY;
    float m = vv[0];
#pragma unroll
    for (int i = 1; i < 8; ++i) m = fmaxf(m, vv[i]);
#pragma unroll
    for (int o = 4; o; o >>= 1) m = fmaxf(m, __shfl_xor(m, o));
    float sm = 0.f;
#pragma unroll
    for (int i = 0; i < 8; ++i) sm += (act && c0 + i < NC) ? expf(vv[i] - m) : 0.f;
#pragma unroll
    for (int o = 4; o; o >>= 1) sm += __shfl_xor(sm, o);
    float lg = logf(sm);
    if (g == 0 && act) {
#pragma unroll
        for (int i = 0; i < 8; ++i) {
            int c = c0 + i;
            if (c < NC) so[nloc * NC + c] = vv[i] - m - lg;
        }
    }
    __syncthreads();
    // coalesced block write: 8 nodes x 41 floats = 328 floats = 82 float4
    float4* ob = (float4*)(out + (size_t)blockIdx.x * (8 * NC));
    const float4* sb = (const float4*)so;
    if (tid < 2 * NC) ob[tid] = sb[tid];
}

extern "C" void kernel_launch(void* const* d_in, const int* in_sizes, int n_in,
                              void* d_out, int out_size, void* d_ws, size_t ws_size,
                              hipStream_t stream) {
    const float* x  = (const float*)d_in[0];
    const float* W1 = (const float*)d_in[1];
    const float* b1 = (const float*)d_in[2];
    const float* W2 = (const float*)d_in[3];
    const float* b2 = (const float*)d_in[4];
    const int*   ei = (const int*)d_in[5];
    const int* src = ei;
    const int* dst = ei + N_EDGES;
    float* out = (float*)d_out;

    char* ws = (char*)d_ws;
    int* cnt  = (int*)ws;                                      // N ints (count = degree)
    int* eidx = (int*)(ws + (1u << 20));                       // N*CAP ints (12.8 MB)
    unsigned short* xb = (unsigned short*)(ws + (15u << 20));  // N*128 bf16 (unscaled)
    unsigned short* R  = (unsigned short*)(ws + (41u << 20));  // N*128 bf16 (agg'd)
    unsigned short* h2 = (unsigned short*)(ws + (67u << 20));  // N*48 bf16 (pre-scaled)

    // bucket-CSR build + x->bf16 (interleaved streams; cnt becomes degree)
    hipMemsetAsync(cnt, 0, N_NODES * sizeof(int), stream);
    k_build<<<BLDB, 256, 0, stream>>>(x, xb, src, dst, cnt, eidx);

    // layer-1 aggregation (dinv inline from cnt), then streaming dual-GEMM
    k_aggx<<<N_NODES / 16, 256, 0, stream>>>(xb, cnt, eidx, R);
    k_mm<<<1024, 512, 0, stream>>>(R, W1, b1, W2, cnt, h2);

    // layer-2 aggregation + log_softmax (coalesced output)
    k_gather2<<<N_NODES / 8, 256, 0, stream>>>(h2, out, cnt, eidx, b2);
}